// Round 5
// baseline (833.528 us; speedup 1.0000x reference)
//
#include <hip/hip_runtime.h>
#include <hip/hip_bf16.h>
#include <hip/hip_cooperative_groups.h>
#include <cstdint>

namespace cg = cooperative_groups;

#define KDIM 1024
#define BDIM 8192
#define VDIM 2
#define NBLK 16  // KDIM / 64

typedef __attribute__((ext_vector_type(8))) short short8;
typedef __attribute__((ext_vector_type(4))) float f32x4;

__device__ inline unsigned short f2bf(float x) {
  unsigned u = __builtin_bit_cast(unsigned, x);
  u = (u + 0x7FFFu + ((u >> 16) & 1u)) >> 16;
  return (unsigned short)u;
}

// Scratch layout inside the Mbf region (floats): per-level P^T buffers
#define SCR_L1 0        //  8 * 64*64   = 32768
#define SCR_L2 32768    //  4 * 128*128 = 65536
#define SCR_L3 98304    //  2 * 256*256 = 131072
#define SCR_L4 229376   //  1 * 512*512 = 262144
#define SCR_TOTAL 491520

// ---------------------------------------------------------------------------
// Cooperative inversion: zero + diag + 4 doubling levels in ONE kernel.
// MT[j][i] = M[i][j], M = (I-A)^{-1} unit-lower.
// ---------------------------------------------------------------------------
template <int H>
__device__ void comb_level(const float* __restrict__ A, float* __restrict__ MT,
                           float* __restrict__ Pt, int wg, int tid,
                           float (*Ls)[68], float (*Rs)[68],
                           cg::grid_group& grid) {
  constexpr int T = H >> 6;
  constexpr int CMB = (NBLK / T) >> 1;
  constexpr int NT = CMB * T * T * T;

  const int k4 = tid & 15, rw = tid >> 4;
  const int tm = tid >> 4, tn = tid & 15;

  // ---- P phase: Pt[j][r] += sum_c MT11[j][c] * A21[r][c] ----
  if (wg < NT) {
    int b = wg;
    const int kc = b % T; b /= T;
    const int rt = b % T; b /= T;
    const int jt = b % T; b /= T;
    const int c = b;
    const int base = c * 2 * H;
#pragma unroll
    for (int p = 0; p < 4; ++p) {
      const int m = p * 16 + rw;
      float4 lv = *(const float4*)(MT + (size_t)(base + jt * 64 + m) * KDIM +
                                   base + kc * 64 + 4 * k4);
      Ls[4 * k4 + 0][m] = lv.x;
      Ls[4 * k4 + 1][m] = lv.y;
      Ls[4 * k4 + 2][m] = lv.z;
      Ls[4 * k4 + 3][m] = lv.w;
      float4 rv = *(const float4*)(A + (size_t)(base + H + rt * 64 + m) * KDIM +
                                   base + kc * 64 + 4 * k4);
      Rs[4 * k4 + 0][m] = rv.x;
      Rs[4 * k4 + 1][m] = rv.y;
      Rs[4 * k4 + 2][m] = rv.z;
      Rs[4 * k4 + 3][m] = rv.w;
    }
    __syncthreads();
    float acc[4][4];
#pragma unroll
    for (int a = 0; a < 4; ++a)
#pragma unroll
      for (int bb = 0; bb < 4; ++bb) acc[a][bb] = 0.f;
#pragma unroll 4
    for (int k = 0; k < 64; ++k) {
      float4 av = *(const float4*)&Ls[k][4 * tm];
      float4 bv = *(const float4*)&Rs[k][4 * tn];
      const float aa[4] = {av.x, av.y, av.z, av.w};
      const float bb4[4] = {bv.x, bv.y, bv.z, bv.w};
#pragma unroll
      for (int a = 0; a < 4; ++a)
#pragma unroll
        for (int bb = 0; bb < 4; ++bb) acc[a][bb] += aa[a] * bb4[bb];
    }
    float* P0 = Pt + (size_t)c * H * H;
#pragma unroll
    for (int a = 0; a < 4; ++a)
#pragma unroll
      for (int bb = 0; bb < 4; ++bb)
        unsafeAtomicAdd(
            P0 + (size_t)(jt * 64 + 4 * tm + a) * H + rt * 64 + 4 * tn + bb,
            acc[a][bb]);
  }
  grid.sync();

  // ---- Q phase: MT21t[j][r] += sum_c Pt[j][c] * MT22[c][r] ----
  if (wg < NT) {
    int b = wg;
    const int kc = b % T; b /= T;
    const int rt = b % T; b /= T;
    const int jt = b % T; b /= T;
    const int c = b;
    const int base = c * 2 * H;
    const float* P0 = Pt + (size_t)c * H * H;
#pragma unroll
    for (int p = 0; p < 4; ++p) {
      const int m = p * 16 + rw;
      float4 lv =
          *(const float4*)(P0 + (size_t)(jt * 64 + m) * H + kc * 64 + 4 * k4);
      Ls[4 * k4 + 0][m] = lv.x;
      Ls[4 * k4 + 1][m] = lv.y;
      Ls[4 * k4 + 2][m] = lv.z;
      Ls[4 * k4 + 3][m] = lv.w;
      const int kk = p * 16 + rw;
      *(float4*)&Rs[kk][4 * k4] =
          *(const float4*)(MT + (size_t)(base + H + kc * 64 + kk) * KDIM +
                           base + H + rt * 64 + 4 * k4);
    }
    __syncthreads();
    float acc[4][4];
#pragma unroll
    for (int a = 0; a < 4; ++a)
#pragma unroll
      for (int bb = 0; bb < 4; ++bb) acc[a][bb] = 0.f;
#pragma unroll 4
    for (int k = 0; k < 64; ++k) {
      float4 av = *(const float4*)&Ls[k][4 * tm];
      float4 bv = *(const float4*)&Rs[k][4 * tn];
      const float aa[4] = {av.x, av.y, av.z, av.w};
      const float bb4[4] = {bv.x, bv.y, bv.z, bv.w};
#pragma unroll
      for (int a = 0; a < 4; ++a)
#pragma unroll
        for (int bb = 0; bb < 4; ++bb) acc[a][bb] += aa[a] * bb4[bb];
    }
#pragma unroll
    for (int a = 0; a < 4; ++a)
#pragma unroll
      for (int bb = 0; bb < 4; ++bb)
        unsafeAtomicAdd(MT + (size_t)(base + jt * 64 + 4 * tm + a) * KDIM +
                            base + H + rt * 64 + 4 * tn + bb,
                        acc[a][bb]);
  }
  grid.sync();
}

__global__ __launch_bounds__(256) void invert_all(const float* __restrict__ A,
                                                  float* __restrict__ MT,
                                                  float* __restrict__ scr) {
  cg::grid_group grid = cg::this_grid();
  __shared__ float Ls[64][68];
  __shared__ float Rs[64][68];
  const int wg = blockIdx.x;
  const int tid = threadIdx.x;

  // ---- Phase 0: zero MT (atomic targets + M's zero upper tri) + scratch ----
  {
    const float4 z4 = make_float4(0.f, 0.f, 0.f, 0.f);
    const int gid = wg * 256 + tid;
    const int nth = 512 * 256;
    for (int i = gid; i < KDIM * KDIM / 4; i += nth)
      *(float4*)(MT + 4 * (size_t)i) = z4;
    for (int i = gid; i < SCR_TOTAL / 4; i += nth)
      *(float4*)(scr + 4 * (size_t)i) = z4;
  }
  grid.sync();

  // ---- Phase 1: invert 16 diagonal 64x64 blocks ----
  if (wg < NBLK) {
    float* As = (float*)Ls;  // 4096 floats fit in Ls
    const int base = wg * 64;
    for (int i = tid; i < 1024; i += 256) {
      const int r = i >> 4, c4 = i & 15;
      *(float4*)(As + r * 64 + 4 * c4) =
          *(const float4*)(A + (size_t)(base + r) * KDIM + base + 4 * c4);
    }
    __syncthreads();
    if (tid < 64) {
      const int c = tid;
      float m[64];
#pragma unroll
      for (int r = 0; r < 64; ++r) m[r] = (r == c) ? 1.f : 0.f;
#pragma unroll
      for (int r = 1; r < 64; ++r) {
        float acc0 = 0.f, acc1 = 0.f;
#pragma unroll
        for (int i = 0; i < 64; ++i) {
          if (i >= r) break;
          if (i & 1) acc1 += As[r * 64 + i] * m[i];
          else       acc0 += As[r * 64 + i] * m[i];
        }
        const float v = acc0 + acc1;
        m[r] = (r > c) ? v : m[r];
      }
#pragma unroll
      for (int r = 0; r < 64; r += 4) {
        float4 v = make_float4(m[r], m[r + 1], m[r + 2], m[r + 3]);
        *(float4*)(MT + (size_t)(base + c) * KDIM + base + r) = v;
      }
    }
  }
  grid.sync();

  // ---- Phases 2-9: recursive doubling ----
  comb_level<64>(A, MT, scr + SCR_L1, wg, tid, Ls, Rs, grid);
  comb_level<128>(A, MT, scr + SCR_L2, wg, tid, Ls, Rs, grid);
  comb_level<256>(A, MT, scr + SCR_L3, wg, tid, Ls, Rs, grid);
  comb_level<512>(A, MT, scr + SCR_L4, wg, tid, Ls, Rs, grid);
}

// ---------------------------------------------------------------------------
// Mbf[i][k] = bf16(MT[k][i])  — transpose+convert, 64x64 tiles.
// ---------------------------------------------------------------------------
__global__ __launch_bounds__(256) void mt2bf(const float* __restrict__ MT,
                                             unsigned short* __restrict__ Mbf) {
  const int ib = blockIdx.x & 15;
  const int jb = blockIdx.x >> 4;
  const int i0 = ib * 64, j0 = jb * 64;
  __shared__ float tile[64][65];

  const int tr = threadIdx.x >> 4;
  const int tc = threadIdx.x & 15;
#pragma unroll
  for (int p = 0; p < 4; ++p) {
    const int rj = p * 16 + tr;
    float4 v = *(const float4*)(MT + (size_t)(j0 + rj) * KDIM + i0 + 4 * tc);
    tile[rj][4 * tc + 0] = v.x;
    tile[rj][4 * tc + 1] = v.y;
    tile[rj][4 * tc + 2] = v.z;
    tile[rj][4 * tc + 3] = v.w;
  }
  __syncthreads();
#pragma unroll
  for (int p = 0; p < 4; ++p) {
    const int il = p * 16 + tr;
    ushort4 o;
    o.x = f2bf(tile[4 * tc + 0][il]);
    o.y = f2bf(tile[4 * tc + 1][il]);
    o.z = f2bf(tile[4 * tc + 2][il]);
    o.w = f2bf(tile[4 * tc + 3][il]);
    *(ushort4*)(Mbf + (size_t)(i0 + il) * KDIM + j0 + 4 * tc) = o;
  }
}

// ---------------------------------------------------------------------------
// bf16 MFMA GEMM, double-buffered K-loop (one barrier per k-block).
// C[b][i] = sum_k Z[b][k] * Mbf[i][k]   (NT), 128x128 tile, 4 waves.
// ---------------------------------------------------------------------------
#define LDB 72

__global__ __launch_bounds__(256) void gemm_mfma(
    const float* __restrict__ Z, const unsigned short* __restrict__ Mbf,
    float* __restrict__ C) {
  __shared__ unsigned short As[2][128][LDB];
  __shared__ unsigned short Bs[2][128][LDB];

  const int wg = blockIdx.x;
  const int t7 = wg & 7;
  const int ni = (t7 & 1) ? (7 - (t7 >> 1)) : (t7 >> 1);
  const int xb = wg >> 3;
  const int b0 = xb * 128;
  const int i0 = ni * 128;

  const int tid = threadIdx.x;
  const int w = tid >> 6;
  const int lane = tid & 63;
  const int wr = w >> 1, wc = w & 1;
  const int mlane = lane & 15;
  const int q = lane >> 4;

  const int rq = tid >> 4, kq = tid & 15;
  const int cb = tid >> 3, ck = tid & 7;

  f32x4 acc[4][4];
#pragma unroll
  for (int a = 0; a < 4; ++a)
#pragma unroll
    for (int b = 0; b < 4; ++b) acc[a][b] = (f32x4){0.f, 0.f, 0.f, 0.f};

  const int nkb = 2 * (ni + 1);

  float4 zr[8];
  uint4 br[4];

  // prologue: load k-block 0 into regs, stage to buf 0
#pragma unroll
  for (int p = 0; p < 8; ++p)
    zr[p] = *(const float4*)(Z + (size_t)(b0 + p * 16 + rq) * KDIM + 4 * kq);
#pragma unroll
  for (int p = 0; p < 4; ++p)
    br[p] = *(const uint4*)(Mbf + (size_t)(i0 + p * 32 + cb) * KDIM + 8 * ck);
#pragma unroll
  for (int p = 0; p < 8; ++p) {
    ushort4 o;
    o.x = f2bf(zr[p].x);
    o.y = f2bf(zr[p].y);
    o.z = f2bf(zr[p].z);
    o.w = f2bf(zr[p].w);
    *(ushort4*)&As[0][p * 16 + rq][4 * kq] = o;
  }
#pragma unroll
  for (int p = 0; p < 4; ++p) *(uint4*)&Bs[0][p * 32 + cb][8 * ck] = br[p];
  __syncthreads();

  for (int kb = 0; kb < nkb; ++kb) {
    const int cur = kb & 1;
    const bool more = (kb + 1 < nkb);
    if (more) {
      const int k0 = (kb + 1) * 64;
#pragma unroll
      for (int p = 0; p < 8; ++p)
        zr[p] = *(const float4*)(Z + (size_t)(b0 + p * 16 + rq) * KDIM + k0 +
                                 4 * kq);
#pragma unroll
      for (int p = 0; p < 4; ++p)
        br[p] = *(const uint4*)(Mbf + (size_t)(i0 + p * 32 + cb) * KDIM + k0 +
                                8 * ck);
    }
    // MFMA on buf cur
#pragma unroll
    for (int ks = 0; ks < 2; ++ks) {
      const int kf = ks * 32 + q * 8;
      short8 av[4], bv[4];
#pragma unroll
      for (int a = 0; a < 4; ++a)
        av[a] = *(const short8*)&As[cur][wr * 64 + 16 * a + mlane][kf];
#pragma unroll
      for (int b = 0; b < 4; ++b)
        bv[b] = *(const short8*)&Bs[cur][wc * 64 + 16 * b + mlane][kf];
#pragma unroll
      for (int a = 0; a < 4; ++a)
#pragma unroll
        for (int b = 0; b < 4; ++b)
          acc[a][b] = __builtin_amdgcn_mfma_f32_16x16x32_bf16(av[a], bv[b],
                                                              acc[a][b], 0, 0, 0);
    }
    if (more) {
#pragma unroll
      for (int p = 0; p < 8; ++p) {
        ushort4 o;
        o.x = f2bf(zr[p].x);
        o.y = f2bf(zr[p].y);
        o.z = f2bf(zr[p].z);
        o.w = f2bf(zr[p].w);
        *(ushort4*)&As[cur ^ 1][p * 16 + rq][4 * kq] = o;
      }
#pragma unroll
      for (int p = 0; p < 4; ++p)
        *(uint4*)&Bs[cur ^ 1][p * 32 + cb][8 * ck] = br[p];
    }
    __syncthreads();
  }

#pragma unroll
  for (int a = 0; a < 4; ++a) {
    const int row0 = b0 + wr * 64 + 16 * a + q * 4;
#pragma unroll
    for (int b = 0; b < 4; ++b) {
      const int col = i0 + wc * 64 + 16 * b + mlane;
      float* Cp = C + (size_t)row0 * KDIM + col;
      Cp[0 * KDIM] = acc[a][b][0];
      Cp[1 * KDIM] = acc[a][b][1];
      Cp[2 * KDIM] = acc[a][b][2];
      Cp[3 * KDIM] = acc[a][b][3];
    }
  }
}

// ---------------------------------------------------------------------------
// Per-sample rank-1 correction, in place on d_out.
// u[b,:] = g[b,:] + (v - g[b,t]) * MT[t,:]
// ---------------------------------------------------------------------------
__global__ __launch_bounds__(256) void correction_k(
    const float* __restrict__ z, const int* __restrict__ tgt,
    const int* __restrict__ var, const float* __restrict__ means,
    const float* __restrict__ lsc, const float* __restrict__ MT,
    float* __restrict__ out) {
  const int b = blockIdx.x;
  const int t = tgt[b];
  if (t < 0) return;
  const int v = var[b];
  const float mval = means[t * VDIM + v];
  const float sval = expf(lsc[t * VDIM + v]);
  const float zv = z[(size_t)b * KDIM + t];
  const float gt = out[(size_t)b * KDIM + t];
  const float coef = (mval + sval * zv) - gt;
  __syncthreads();
  const int i = threadIdx.x * 4;
  float4 g = *(float4*)(out + (size_t)b * KDIM + i);
  float4 mt = *(const float4*)(MT + (size_t)t * KDIM + i);
  g.x += coef * mt.x;
  g.y += coef * mt.y;
  g.z += coef * mt.z;
  g.w += coef * mt.w;
  *(float4*)(out + (size_t)b * KDIM + i) = g;
}

// ---------------------------------------------------------------------------
extern "C" void kernel_launch(void* const* d_in, const int* in_sizes, int n_in,
                              void* d_out, int out_size, void* d_ws,
                              size_t ws_size, hipStream_t stream) {
  const float* z = (const float*)d_in[0];
  const int* tgt = (const int*)d_in[1];
  const int* var = (const int*)d_in[2];
  const float* A = (const float*)d_in[3];
  const float* means = (const float*)d_in[4];
  const float* lsc = (const float*)d_in[5];
  float* out = (float*)d_out;

  float* MT = (float*)d_ws;  // 4 MB fp32 (M^T = column-major M)
  float* scr = (float*)((char*)d_ws + (size_t)KDIM * KDIM * 4);  // 2 MB region
  unsigned short* Mbf = (unsigned short*)scr;  // reused after inversion

  {
    const float* Aarg = A;
    float* MTarg = MT;
    float* scrarg = scr;
    void* args[3] = {(void*)&Aarg, (void*)&MTarg, (void*)&scrarg};
    hipLaunchCooperativeKernel((void*)invert_all, dim3(512), dim3(256), args, 0,
                               stream);
  }

  hipLaunchKernelGGL(mt2bf, dim3(NBLK * NBLK), dim3(256), 0, stream, MT, Mbf);
  hipLaunchKernelGGL(gemm_mfma, dim3((BDIM / 128) * (KDIM / 128)), dim3(256), 0,
                     stream, z, Mbf, out);
  hipLaunchKernelGGL(correction_k, dim3(BDIM), dim3(256), 0, stream, z, tgt,
                     var, means, lsc, MT, out);
}

// Round 6
// 298.708 us; speedup vs baseline: 2.7904x; 2.7904x over previous
//
#include <hip/hip_runtime.h>
#include <hip/hip_bf16.h>
#include <cstdint>

#define KDIM 1024
#define BDIM 8192
#define VDIM 2
#define NBLK 16  // KDIM / 64

typedef __attribute__((ext_vector_type(8))) short short8;
typedef __attribute__((ext_vector_type(4))) float f32x4;

__device__ inline unsigned short f2bf(float x) {
  unsigned u = __builtin_bit_cast(unsigned, x);
  u = (u + 0x7FFFu + ((u >> 16) & 1u)) >> 16;
  return (unsigned short)u;
}

// ---------------------------------------------------------------------------
// inv_base: one WG per 256-wide diagonal super-block (4 WGs total).
//   Phase A: invert the 4 diagonal 64x64 unit-lower blocks (thread/column).
//   Phase B: two h=64 combines   (M21 = M22*A21*M11), P held in LDS.
//   Phase C: one h=128 combine, P held in LDS, triangular chunk skip.
// MT[j][i] = M[i][j]. Only the upper (i>=j) block-triangle of MT is written.
// ---------------------------------------------------------------------------
__global__ __launch_bounds__(256) void inv_base(const float* __restrict__ A,
                                                float* __restrict__ MT) {
  __shared__ float Ps[128][132];  // 67.6 KB; doubles as As (16384 fl) in phase A
  __shared__ float Ls[64][68];
  __shared__ float Rs[64][68];

  const int sbase = blockIdx.x * 256;
  const int tid = threadIdx.x;
  const int k4 = tid & 15, rw = tid >> 4;
  const int tm = tid >> 4, tn = tid & 15;

  // ---------------- Phase A: 4 diagonal 64x64 inversions ----------------
  {
    float* As = (float*)Ps;  // 4 blocks * 4096 floats
    const int g = tid >> 6, lane = tid & 63;
    const int bb = sbase + g * 64;
    for (int r = 0; r < 64; ++r)
      As[g * 4096 + r * 64 + lane] = A[(size_t)(bb + r) * KDIM + bb + lane];
    __syncthreads();

    const int c = lane;
    float m[64];
#pragma unroll
    for (int r = 0; r < 64; ++r) m[r] = (r == c) ? 1.f : 0.f;
#pragma unroll
    for (int r = 1; r < 64; ++r) {
      float acc0 = 0.f, acc1 = 0.f;
#pragma unroll
      for (int i = 0; i < 64; ++i) {
        if (i >= r) break;
        if (i & 1) acc1 += As[g * 4096 + r * 64 + i] * m[i];
        else       acc0 += As[g * 4096 + r * 64 + i] * m[i];
      }
      const float v = acc0 + acc1;
      m[r] = (r > c) ? v : m[r];
    }
    // MT[bb+c][bb+r] = T_g[r][c]
#pragma unroll
    for (int r = 0; r < 64; r += 4) {
      float4 v = make_float4(m[r], m[r + 1], m[r + 2], m[r + 3]);
      *(float4*)(MT + (size_t)(bb + c) * KDIM + bb + r) = v;
    }
  }
  __threadfence();
  __syncthreads();

  // ---------------- Phase B: two h=64 combines ----------------
  for (int cmb = 0; cmb < 2; ++cmb) {
    const int cb = sbase + 128 * cmb;
    __syncthreads();
    // P: Pt[j][r] = sum_c MT11[j][c] * A21[r][c]
#pragma unroll
    for (int p = 0; p < 4; ++p) {
      const int m = p * 16 + rw;
      float4 lv = *(const float4*)(MT + (size_t)(cb + m) * KDIM + cb + 4 * k4);
      Ls[4 * k4 + 0][m] = lv.x;
      Ls[4 * k4 + 1][m] = lv.y;
      Ls[4 * k4 + 2][m] = lv.z;
      Ls[4 * k4 + 3][m] = lv.w;
      float4 rv =
          *(const float4*)(A + (size_t)(cb + 64 + m) * KDIM + cb + 4 * k4);
      Rs[4 * k4 + 0][m] = rv.x;
      Rs[4 * k4 + 1][m] = rv.y;
      Rs[4 * k4 + 2][m] = rv.z;
      Rs[4 * k4 + 3][m] = rv.w;
    }
    __syncthreads();
    float acc[4][4];
#pragma unroll
    for (int a = 0; a < 4; ++a)
#pragma unroll
      for (int b = 0; b < 4; ++b) acc[a][b] = 0.f;
#pragma unroll 4
    for (int k = 0; k < 64; ++k) {
      float4 av = *(const float4*)&Ls[k][4 * tm];
      float4 bv = *(const float4*)&Rs[k][4 * tn];
      const float aa[4] = {av.x, av.y, av.z, av.w};
      const float bb4[4] = {bv.x, bv.y, bv.z, bv.w};
#pragma unroll
      for (int a = 0; a < 4; ++a)
#pragma unroll
        for (int b = 0; b < 4; ++b) acc[a][b] += aa[a] * bb4[b];
    }
    // store P transposed: Ps[r][j] = Pt[j][r]
#pragma unroll
    for (int a = 0; a < 4; ++a)
#pragma unroll
      for (int b = 0; b < 4; ++b) Ps[4 * tn + b][4 * tm + a] = acc[a][b];
    __syncthreads();
    // Q: out[j][r] = sum_c Pt[j][c] * MT22[c][r]
#pragma unroll
    for (int p = 0; p < 4; ++p) {
      const int kk = p * 16 + rw;
      *(float4*)&Rs[kk][4 * k4] =
          *(const float4*)(MT + (size_t)(cb + 64 + kk) * KDIM + cb + 64 + 4 * k4);
    }
    __syncthreads();
#pragma unroll
    for (int a = 0; a < 4; ++a)
#pragma unroll
      for (int b = 0; b < 4; ++b) acc[a][b] = 0.f;
#pragma unroll 4
    for (int k = 0; k < 64; ++k) {
      float4 av = *(const float4*)&Ps[k][4 * tm];
      float4 bv = *(const float4*)&Rs[k][4 * tn];
      const float aa[4] = {av.x, av.y, av.z, av.w};
      const float bb4[4] = {bv.x, bv.y, bv.z, bv.w};
#pragma unroll
      for (int a = 0; a < 4; ++a)
#pragma unroll
        for (int b = 0; b < 4; ++b) acc[a][b] += aa[a] * bb4[b];
    }
#pragma unroll
    for (int a = 0; a < 4; ++a) {
      float4 o = make_float4(acc[a][0], acc[a][1], acc[a][2], acc[a][3]);
      *(float4*)(MT + (size_t)(cb + 4 * tm + a) * KDIM + cb + 64 + 4 * tn) = o;
    }
  }
  __threadfence();
  __syncthreads();

  // ---------------- Phase C: h=128 combine ----------------
  // P2[j][r] = sum_c MT11[j][c]*A21[r][c], j,r in [0,128); skip kc<jt (zero)
  for (int tile = 0; tile < 4; ++tile) {
    const int jt = tile >> 1, rt = tile & 1;
    float acc[4][4];
#pragma unroll
    for (int a = 0; a < 4; ++a)
#pragma unroll
      for (int b = 0; b < 4; ++b) acc[a][b] = 0.f;
    for (int kc = jt; kc < 2; ++kc) {
      __syncthreads();
#pragma unroll
      for (int p = 0; p < 4; ++p) {
        const int m = p * 16 + rw;
        float4 lv = *(const float4*)(MT + (size_t)(sbase + jt * 64 + m) * KDIM +
                                     sbase + kc * 64 + 4 * k4);
        Ls[4 * k4 + 0][m] = lv.x;
        Ls[4 * k4 + 1][m] = lv.y;
        Ls[4 * k4 + 2][m] = lv.z;
        Ls[4 * k4 + 3][m] = lv.w;
        float4 rv =
            *(const float4*)(A + (size_t)(sbase + 128 + rt * 64 + m) * KDIM +
                             sbase + kc * 64 + 4 * k4);
        Rs[4 * k4 + 0][m] = rv.x;
        Rs[4 * k4 + 1][m] = rv.y;
        Rs[4 * k4 + 2][m] = rv.z;
        Rs[4 * k4 + 3][m] = rv.w;
      }
      __syncthreads();
#pragma unroll 4
      for (int k = 0; k < 64; ++k) {
        float4 av = *(const float4*)&Ls[k][4 * tm];
        float4 bv = *(const float4*)&Rs[k][4 * tn];
        const float aa[4] = {av.x, av.y, av.z, av.w};
        const float bb4[4] = {bv.x, bv.y, bv.z, bv.w};
#pragma unroll
        for (int a = 0; a < 4; ++a)
#pragma unroll
          for (int b = 0; b < 4; ++b) acc[a][b] += aa[a] * bb4[b];
      }
    }
    __syncthreads();
#pragma unroll
    for (int a = 0; a < 4; ++a)
#pragma unroll
      for (int b = 0; b < 4; ++b)
        Ps[rt * 64 + 4 * tn + b][jt * 64 + 4 * tm + a] = acc[a][b];
  }
  // Q2: out[j][r] = sum_c P2[j][c]*MT22[c][r]; skip kc>rt (zero)
  for (int tile = 0; tile < 4; ++tile) {
    const int jt = tile >> 1, rt = tile & 1;
    float acc[4][4];
#pragma unroll
    for (int a = 0; a < 4; ++a)
#pragma unroll
      for (int b = 0; b < 4; ++b) acc[a][b] = 0.f;
    for (int kc = 0; kc <= rt; ++kc) {
      __syncthreads();
#pragma unroll
      for (int p = 0; p < 4; ++p) {
        const int kk = p * 16 + rw;
        *(float4*)&Rs[kk][4 * k4] =
            *(const float4*)(MT + (size_t)(sbase + 128 + kc * 64 + kk) * KDIM +
                             sbase + 128 + rt * 64 + 4 * k4);
      }
      __syncthreads();
#pragma unroll 4
      for (int k = 0; k < 64; ++k) {
        float4 av = *(const float4*)&Ps[kc * 64 + k][jt * 64 + 4 * tm];
        float4 bv = *(const float4*)&Rs[k][4 * tn];
        const float aa[4] = {av.x, av.y, av.z, av.w};
        const float bb4[4] = {bv.x, bv.y, bv.z, bv.w};
#pragma unroll
        for (int a = 0; a < 4; ++a)
#pragma unroll
          for (int b = 0; b < 4; ++b) acc[a][b] += aa[a] * bb4[b];
      }
    }
#pragma unroll
    for (int a = 0; a < 4; ++a) {
      float4 o = make_float4(acc[a][0], acc[a][1], acc[a][2], acc[a][3]);
      *(float4*)(MT + (size_t)(sbase + jt * 64 + 4 * tm + a) * KDIM + sbase +
                 128 + rt * 64 + 4 * tn) = o;
    }
  }
}

// ---------------------------------------------------------------------------
// comb_p2: Pt[j][r] = sum_c MT11[j][c] * A21[r][c]   (full-K per tile,
// triangular skip kc>=jt, plain stores — no atomics, no pre-zero).
// grid = combines * t * t,  t = h/64.
// ---------------------------------------------------------------------------
__global__ __launch_bounds__(256) void comb_p2(const float* __restrict__ A,
                                               const float* __restrict__ MT,
                                               float* __restrict__ Pt, int h) {
  const int t = h >> 6;
  int b = blockIdx.x;
  const int rt = b % t; b /= t;
  const int jt = b % t; b /= t;
  const int c = b;
  const int base = c * 2 * h;

  __shared__ float Ls[64][68];
  __shared__ float Rs[64][68];
  const int tid = threadIdx.x;
  const int k4 = tid & 15, rw = tid >> 4;
  const int tm = tid >> 4, tn = tid & 15;

  float acc[4][4];
#pragma unroll
  for (int a = 0; a < 4; ++a)
#pragma unroll
    for (int bb = 0; bb < 4; ++bb) acc[a][bb] = 0.f;

  for (int kc = jt; kc < t; ++kc) {
    __syncthreads();
#pragma unroll
    for (int p = 0; p < 4; ++p) {
      const int m = p * 16 + rw;
      float4 lv = *(const float4*)(MT + (size_t)(base + jt * 64 + m) * KDIM +
                                   base + kc * 64 + 4 * k4);
      Ls[4 * k4 + 0][m] = lv.x;
      Ls[4 * k4 + 1][m] = lv.y;
      Ls[4 * k4 + 2][m] = lv.z;
      Ls[4 * k4 + 3][m] = lv.w;
      float4 rv = *(const float4*)(A + (size_t)(base + h + rt * 64 + m) * KDIM +
                                   base + kc * 64 + 4 * k4);
      Rs[4 * k4 + 0][m] = rv.x;
      Rs[4 * k4 + 1][m] = rv.y;
      Rs[4 * k4 + 2][m] = rv.z;
      Rs[4 * k4 + 3][m] = rv.w;
    }
    __syncthreads();
#pragma unroll 4
    for (int k = 0; k < 64; ++k) {
      float4 av = *(const float4*)&Ls[k][4 * tm];
      float4 bv = *(const float4*)&Rs[k][4 * tn];
      const float aa[4] = {av.x, av.y, av.z, av.w};
      const float bb4[4] = {bv.x, bv.y, bv.z, bv.w};
#pragma unroll
      for (int a = 0; a < 4; ++a)
#pragma unroll
        for (int bb = 0; bb < 4; ++bb) acc[a][bb] += aa[a] * bb4[bb];
    }
  }
#pragma unroll
  for (int a = 0; a < 4; ++a) {
    float4 o = make_float4(acc[a][0], acc[a][1], acc[a][2], acc[a][3]);
    *(float4*)(Pt + (size_t)c * h * h + (size_t)(jt * 64 + 4 * tm + a) * h +
               rt * 64 + 4 * tn) = o;
  }
}

// ---------------------------------------------------------------------------
// comb_q2: MT21t[j][r] = sum_c Pt[j][c] * MT22[c][r]   (skip kc>rt).
// ---------------------------------------------------------------------------
__global__ __launch_bounds__(256) void comb_q2(float* __restrict__ MT,
                                               const float* __restrict__ Pt,
                                               int h) {
  const int t = h >> 6;
  int b = blockIdx.x;
  const int rt = b % t; b /= t;
  const int jt = b % t; b /= t;
  const int c = b;
  const int base = c * 2 * h;
  const float* P0 = Pt + (size_t)c * h * h;

  __shared__ float Ls[64][68];
  __shared__ float Rs[64][68];
  const int tid = threadIdx.x;
  const int k4 = tid & 15, rw = tid >> 4;
  const int tm = tid >> 4, tn = tid & 15;

  float acc[4][4];
#pragma unroll
  for (int a = 0; a < 4; ++a)
#pragma unroll
    for (int bb = 0; bb < 4; ++bb) acc[a][bb] = 0.f;

  for (int kc = 0; kc <= rt; ++kc) {
    __syncthreads();
#pragma unroll
    for (int p = 0; p < 4; ++p) {
      const int m = p * 16 + rw;
      float4 lv = *(const float4*)(P0 + (size_t)(jt * 64 + m) * h + kc * 64 + 4 * k4);
      Ls[4 * k4 + 0][m] = lv.x;
      Ls[4 * k4 + 1][m] = lv.y;
      Ls[4 * k4 + 2][m] = lv.z;
      Ls[4 * k4 + 3][m] = lv.w;
      const int kk = p * 16 + rw;
      *(float4*)&Rs[kk][4 * k4] =
          *(const float4*)(MT + (size_t)(base + h + kc * 64 + kk) * KDIM +
                           base + h + rt * 64 + 4 * k4);
    }
    __syncthreads();
#pragma unroll 4
    for (int k = 0; k < 64; ++k) {
      float4 av = *(const float4*)&Ls[k][4 * tm];
      float4 bv = *(const float4*)&Rs[k][4 * tn];
      const float aa[4] = {av.x, av.y, av.z, av.w};
      const float bb4[4] = {bv.x, bv.y, bv.z, bv.w};
#pragma unroll
      for (int a = 0; a < 4; ++a)
#pragma unroll
        for (int bb = 0; bb < 4; ++bb) acc[a][bb] += aa[a] * bb4[bb];
    }
  }
#pragma unroll
  for (int a = 0; a < 4; ++a) {
    float4 o = make_float4(acc[a][0], acc[a][1], acc[a][2], acc[a][3]);
    *(float4*)(MT + (size_t)(base + jt * 64 + 4 * tm + a) * KDIM + base + h +
               rt * 64 + 4 * tn) = o;
  }
}

// ---------------------------------------------------------------------------
// mt2bf: Mbf[i][k] = bf16(MT[k][i]); tiles with ib<jb are structurally zero
// (MT there is unwritten garbage) — write zeros without reading.
// ---------------------------------------------------------------------------
__global__ __launch_bounds__(256) void mt2bf(const float* __restrict__ MT,
                                             unsigned short* __restrict__ Mbf) {
  const int ib = blockIdx.x & 15;
  const int jb = blockIdx.x >> 4;
  const int i0 = ib * 64, j0 = jb * 64;
  const int tr = threadIdx.x >> 4;
  const int tc = threadIdx.x & 15;

  if (ib < jb) {
    const ushort4 z = {0, 0, 0, 0};
#pragma unroll
    for (int p = 0; p < 4; ++p)
      *(ushort4*)(Mbf + (size_t)(i0 + p * 16 + tr) * KDIM + j0 + 4 * tc) = z;
    return;
  }

  __shared__ float tile[64][65];
#pragma unroll
  for (int p = 0; p < 4; ++p) {
    const int rj = p * 16 + tr;
    float4 v = *(const float4*)(MT + (size_t)(j0 + rj) * KDIM + i0 + 4 * tc);
    tile[rj][4 * tc + 0] = v.x;
    tile[rj][4 * tc + 1] = v.y;
    tile[rj][4 * tc + 2] = v.z;
    tile[rj][4 * tc + 3] = v.w;
  }
  __syncthreads();
#pragma unroll
  for (int p = 0; p < 4; ++p) {
    const int il = p * 16 + tr;
    ushort4 o;
    o.x = f2bf(tile[4 * tc + 0][il]);
    o.y = f2bf(tile[4 * tc + 1][il]);
    o.z = f2bf(tile[4 * tc + 2][il]);
    o.w = f2bf(tile[4 * tc + 3][il]);
    *(ushort4*)(Mbf + (size_t)(i0 + il) * KDIM + j0 + 4 * tc) = o;
  }
}

// ---------------------------------------------------------------------------
// bf16 MFMA GEMM, double-buffered K-loop (one barrier per k-block).
// C[b][i] = sum_k Z[b][k] * Mbf[i][k]   (NT), 128x128 tile, 4 waves.
// ---------------------------------------------------------------------------
#define LDB 72

__global__ __launch_bounds__(256) void gemm_mfma(
    const float* __restrict__ Z, const unsigned short* __restrict__ Mbf,
    float* __restrict__ C) {
  __shared__ unsigned short As[2][128][LDB];
  __shared__ unsigned short Bs[2][128][LDB];

  const int wg = blockIdx.x;
  const int t7 = wg & 7;
  const int ni = (t7 & 1) ? (7 - (t7 >> 1)) : (t7 >> 1);
  const int xb = wg >> 3;
  const int b0 = xb * 128;
  const int i0 = ni * 128;

  const int tid = threadIdx.x;
  const int w = tid >> 6;
  const int lane = tid & 63;
  const int wr = w >> 1, wc = w & 1;
  const int mlane = lane & 15;
  const int q = lane >> 4;

  const int rq = tid >> 4, kq = tid & 15;
  const int cb = tid >> 3, ck = tid & 7;

  f32x4 acc[4][4];
#pragma unroll
  for (int a = 0; a < 4; ++a)
#pragma unroll
    for (int b = 0; b < 4; ++b) acc[a][b] = (f32x4){0.f, 0.f, 0.f, 0.f};

  const int nkb = 2 * (ni + 1);

  float4 zr[8];
  uint4 br[4];

#pragma unroll
  for (int p = 0; p < 8; ++p)
    zr[p] = *(const float4*)(Z + (size_t)(b0 + p * 16 + rq) * KDIM + 4 * kq);
#pragma unroll
  for (int p = 0; p < 4; ++p)
    br[p] = *(const uint4*)(Mbf + (size_t)(i0 + p * 32 + cb) * KDIM + 8 * ck);
#pragma unroll
  for (int p = 0; p < 8; ++p) {
    ushort4 o;
    o.x = f2bf(zr[p].x);
    o.y = f2bf(zr[p].y);
    o.z = f2bf(zr[p].z);
    o.w = f2bf(zr[p].w);
    *(ushort4*)&As[0][p * 16 + rq][4 * kq] = o;
  }
#pragma unroll
  for (int p = 0; p < 4; ++p) *(uint4*)&Bs[0][p * 32 + cb][8 * ck] = br[p];
  __syncthreads();

  for (int kb = 0; kb < nkb; ++kb) {
    const int cur = kb & 1;
    const bool more = (kb + 1 < nkb);
    if (more) {
      const int k0 = (kb + 1) * 64;
#pragma unroll
      for (int p = 0; p < 8; ++p)
        zr[p] = *(const float4*)(Z + (size_t)(b0 + p * 16 + rq) * KDIM + k0 +
                                 4 * kq);
#pragma unroll
      for (int p = 0; p < 4; ++p)
        br[p] = *(const uint4*)(Mbf + (size_t)(i0 + p * 32 + cb) * KDIM + k0 +
                                8 * ck);
    }
#pragma unroll
    for (int ks = 0; ks < 2; ++ks) {
      const int kf = ks * 32 + q * 8;
      short8 av[4], bv[4];
#pragma unroll
      for (int a = 0; a < 4; ++a)
        av[a] = *(const short8*)&As[cur][wr * 64 + 16 * a + mlane][kf];
#pragma unroll
      for (int b = 0; b < 4; ++b)
        bv[b] = *(const short8*)&Bs[cur][wc * 64 + 16 * b + mlane][kf];
#pragma unroll
      for (int a = 0; a < 4; ++a)
#pragma unroll
        for (int b = 0; b < 4; ++b)
          acc[a][b] = __builtin_amdgcn_mfma_f32_16x16x32_bf16(av[a], bv[b],
                                                              acc[a][b], 0, 0, 0);
    }
    if (more) {
#pragma unroll
      for (int p = 0; p < 8; ++p) {
        ushort4 o;
        o.x = f2bf(zr[p].x);
        o.y = f2bf(zr[p].y);
        o.z = f2bf(zr[p].z);
        o.w = f2bf(zr[p].w);
        *(ushort4*)&As[cur ^ 1][p * 16 + rq][4 * kq] = o;
      }
#pragma unroll
      for (int p = 0; p < 4; ++p)
        *(uint4*)&Bs[cur ^ 1][p * 32 + cb][8 * ck] = br[p];
    }
    __syncthreads();
  }

#pragma unroll
  for (int a = 0; a < 4; ++a) {
    const int row0 = b0 + wr * 64 + 16 * a + q * 4;
#pragma unroll
    for (int b = 0; b < 4; ++b) {
      const int col = i0 + wc * 64 + 16 * b + mlane;
      float* Cp = C + (size_t)row0 * KDIM + col;
      Cp[0 * KDIM] = acc[a][b][0];
      Cp[1 * KDIM] = acc[a][b][1];
      Cp[2 * KDIM] = acc[a][b][2];
      Cp[3 * KDIM] = acc[a][b][3];
    }
  }
}

// ---------------------------------------------------------------------------
// correction_k: u[b,:] = g[b,:] + (v - g[b,t]) * MT[t,:], masked to i >= t
// (MT[t][i] for i below t's diagonal block is unwritten garbage; true M
// column t is zero there anyway).
// ---------------------------------------------------------------------------
__global__ __launch_bounds__(256) void correction_k(
    const float* __restrict__ z, const int* __restrict__ tgt,
    const int* __restrict__ var, const float* __restrict__ means,
    const float* __restrict__ lsc, const float* __restrict__ MT,
    float* __restrict__ out) {
  const int b = blockIdx.x;
  const int t = tgt[b];
  if (t < 0) return;
  const int v = var[b];
  const float mval = means[t * VDIM + v];
  const float sval = expf(lsc[t * VDIM + v]);
  const float zv = z[(size_t)b * KDIM + t];
  const float gt = out[(size_t)b * KDIM + t];
  const float coef = (mval + sval * zv) - gt;
  __syncthreads();
  const int i = threadIdx.x * 4;
  float4 g = *(float4*)(out + (size_t)b * KDIM + i);
  float4 mt = *(const float4*)(MT + (size_t)t * KDIM + i);
  g.x += (i + 0 >= t) ? coef * mt.x : 0.f;
  g.y += (i + 1 >= t) ? coef * mt.y : 0.f;
  g.z += (i + 2 >= t) ? coef * mt.z : 0.f;
  g.w += (i + 3 >= t) ? coef * mt.w : 0.f;
  *(float4*)(out + (size_t)b * KDIM + i) = g;
}

// ---------------------------------------------------------------------------
extern "C" void kernel_launch(void* const* d_in, const int* in_sizes, int n_in,
                              void* d_out, int out_size, void* d_ws,
                              size_t ws_size, hipStream_t stream) {
  const float* z = (const float*)d_in[0];
  const int* tgt = (const int*)d_in[1];
  const int* var = (const int*)d_in[2];
  const float* A = (const float*)d_in[3];
  const float* means = (const float*)d_in[4];
  const float* lsc = (const float*)d_in[5];
  float* out = (float*)d_out;

  float* MT = (float*)d_ws;  // 4 MB fp32 (M^T = column-major M)
  float* scr = (float*)((char*)d_ws + (size_t)KDIM * KDIM * 4);  // 2 MB region
  unsigned short* Mbf = (unsigned short*)scr;  // reused after inversion

  // diag 256-super-blocks (4 WGs): diag + h=64 + h=128 combines, fused
  hipLaunchKernelGGL(inv_base, dim3(4), dim3(256), 0, stream, A, MT);
  // h=256: 2 combines * 4*4 tiles
  hipLaunchKernelGGL(comb_p2, dim3(32), dim3(256), 0, stream, A, MT, scr, 256);
  hipLaunchKernelGGL(comb_q2, dim3(32), dim3(256), 0, stream, MT, scr, 256);
  // h=512: 1 combine * 8*8 tiles
  hipLaunchKernelGGL(comb_p2, dim3(64), dim3(256), 0, stream, A, MT, scr, 512);
  hipLaunchKernelGGL(comb_q2, dim3(64), dim3(256), 0, stream, MT, scr, 512);

  hipLaunchKernelGGL(mt2bf, dim3(NBLK * NBLK), dim3(256), 0, stream, MT, Mbf);
  hipLaunchKernelGGL(gemm_mfma, dim3((BDIM / 128) * (KDIM / 128)), dim3(256), 0,
                     stream, z, Mbf, out);
  hipLaunchKernelGGL(correction_k, dim3(BDIM), dim3(256), 0, stream, z, tgt,
                     var, means, lsc, MT, out);
}